// Round 3
// baseline (97.530 us; speedup 1.0000x reference)
//
#include <hip/hip_runtime.h>
#include <math.h>

// HybridQuanvolutionEstimator — analytic collapse of the quantum circuit.
//
// z0 = cos(a0+th0); z1 = cos(th1)*cos(a1); z2 = cos(a2); z3 = cos(a3+th3)
// qf[b, 4p..4p+3] = [z0, z0*z1, z0*z1*z2, z1*z2*z3]
// logits = qf @ lin_w.T + lin_b ; out = log_softmax(logits)
//
// R3 changes vs R2:
//  - 8 batch elements per block (grid 512): lin_w is loaded into registers
//    once per block (wave w owns outputs w, w+4, w+8; 48 VGPRs of weights)
//    and reused across all 8 dot-product sets -> 8x less L1-miss/L2 weight
//    traffic (128 MB -> 16 MB). x load becomes one contiguous 25 KB chunk.

#define NB    4096
#define BPB   8                 // batch elements per block
#define GRID  (NB / BPB)        // 512

__global__ __launch_bounds__(256) void hqe_kernel(
    const float* __restrict__ x,       // [B, 784]
    const float* __restrict__ conv_w,  // [4,1,2,2]
    const float* __restrict__ conv_b,  // [4]
    const float* __restrict__ q_theta, // [4]
    const float* __restrict__ lin_w,   // [10, 784]
    const float* __restrict__ lin_b,   // [10]
    float* __restrict__ out)           // [B, 10]
{
    __shared__ __align__(16) float xs[BPB * 784];
    __shared__ __align__(16) float qf[BPB * 784];
    __shared__ float logits_s[BPB][10];

    const int t = threadIdx.x;
    const int wave = t >> 6;
    const int lane = t & 63;
    const int b0 = blockIdx.x * BPB;

    // phase 0: stage x for 8 batch elements (contiguous 25 KB), coalesced
    {
        const float4* src = (const float4*)(x + (size_t)b0 * 784);
        float4* dst = (float4*)xs;
        for (int i = t; i < BPB * 196; i += 256) dst[i] = src[i];
    }
    if (t < BPB * 10) logits_s[t / 10][t % 10] = lin_b[t % 10];

    const float th0 = q_theta[0];
    const float ct1 = __cosf(q_theta[1]);
    const float th3 = q_theta[3];

    // preload this wave's output weights into registers (outputs w, w+4, w+8)
    float4 wreg[3][4];
    int nout = 0;
#pragma unroll
    for (int oi = 0; oi < 3; ++oi) {
        const int o = wave + 4 * oi;
        if (o < 10) {
            const float4* wv = (const float4*)(lin_w + o * 784);
            wreg[oi][0] = wv[lane];
            wreg[oi][1] = wv[64 + lane];
            wreg[oi][2] = wv[128 + lane];
            wreg[oi][3] = (lane < 4) ? wv[192 + lane]
                                     : make_float4(0.f, 0.f, 0.f, 0.f);
            nout = oi + 1;
        }
    }

    __syncthreads();

    // phase 1: each (bb, patch) task computes its 4 features -> LDS
    for (int i = t; i < BPB * 196; i += 256) {
        const int bb = i / 196;
        const int p = i - 196 * bb;
        const int c = p / 49;               // channel (196 = 4*49)
        const int rbase = 4 * p - 196 * c;  // flat spatial index in channel
        const float4 cw = ((const float4*)conv_w)[c];
        const float cb = conv_b[c];
        const float* xb = xs + bb * 784;
        float a[4];
#pragma unroll
        for (int k = 0; k < 4; ++k) {
            const int s = rbase + k;
            const int h = s / 14;
            const int w = s - 14 * h;
            const float* xp = xb + 56 * h + 2 * w;
            a[k] = cb + xp[0] * cw.x + xp[1] * cw.y + xp[28] * cw.z + xp[29] * cw.w;
        }
        const float z0 = __cosf(a[0] + th0);
        const float z1 = ct1 * __cosf(a[1]);
        const float z2 = __cosf(a[2]);
        const float z3 = __cosf(a[3] + th3);
        const float f1 = z0 * z1;
        const float f2 = f1 * z2;
        const float f3 = z1 * z2 * z3;
        ((float4*)qf)[i] = make_float4(z0, f1, f2, f3);
    }

    __syncthreads();

    // phase 2: for each batch element, wave w computes its owned logits as
    // 64-lane dots; qf fragments loaded once per (wave, bb), weights in regs.
    for (int bb = 0; bb < BPB; ++bb) {
        const float4* q4 = (const float4*)(qf + bb * 784);
        const float4 q0 = q4[lane];
        const float4 q1 = q4[64 + lane];
        const float4 q2 = q4[128 + lane];
        const float4 q3 = (lane < 4) ? q4[192 + lane]
                                     : make_float4(0.f, 0.f, 0.f, 0.f);
        for (int oi = 0; oi < nout; ++oi) {
            float s;
            s  = q0.x * wreg[oi][0].x + q0.y * wreg[oi][0].y
               + q0.z * wreg[oi][0].z + q0.w * wreg[oi][0].w;
            s += q1.x * wreg[oi][1].x + q1.y * wreg[oi][1].y
               + q1.z * wreg[oi][1].z + q1.w * wreg[oi][1].w;
            s += q2.x * wreg[oi][2].x + q2.y * wreg[oi][2].y
               + q2.z * wreg[oi][2].z + q2.w * wreg[oi][2].w;
            s += q3.x * wreg[oi][3].x + q3.y * wreg[oi][3].y
               + q3.z * wreg[oi][3].z + q3.w * wreg[oi][3].w;
#pragma unroll
            for (int off = 32; off > 0; off >>= 1)
                s += __shfl_down(s, off, 64);
            if (lane == 0) logits_s[bb][wave + 4 * oi] += s;
        }
    }

    __syncthreads();

    // log-softmax: thread t < 80 -> (bb = t/10, j = t%10)
    if (t < BPB * 10) {
        const int bb = t / 10;
        const int j = t - 10 * bb;
        float m = -INFINITY;
#pragma unroll
        for (int k = 0; k < 10; ++k) m = fmaxf(m, logits_s[bb][k]);
        float sum = 0.0f;
#pragma unroll
        for (int k = 0; k < 10; ++k) sum += __expf(logits_s[bb][k] - m);
        out[(size_t)(b0 + bb) * 10 + j] = logits_s[bb][j] - m - __logf(sum);
    }
}

extern "C" void kernel_launch(void* const* d_in, const int* in_sizes, int n_in,
                              void* d_out, int out_size, void* d_ws, size_t ws_size,
                              hipStream_t stream) {
    const float* x       = (const float*)d_in[0];
    const float* conv_w  = (const float*)d_in[1];
    const float* conv_b  = (const float*)d_in[2];
    const float* q_theta = (const float*)d_in[3];
    const float* lin_w   = (const float*)d_in[4];
    const float* lin_b   = (const float*)d_in[5];
    float* out = (float*)d_out;

    hqe_kernel<<<dim3(GRID), dim3(256), 0, stream>>>(x, conv_w, conv_b, q_theta,
                                                     lin_w, lin_b, out);
}

// Round 4
// 74.871 us; speedup vs baseline: 1.3026x; 1.3026x over previous
//
#include <hip/hip_runtime.h>
#include <math.h>

// HybridQuanvolutionEstimator — analytic circuit collapse + bf16 MFMA linear.
//
// z0=cos(a0+th0); z1=cos(th1)*cos(a1); z2=cos(a2); z3=cos(a3+th3)
// qf[b,4p..4p+3] = [z0, z0*z1, z0*z1*z2, z1*z2*z3]
// logits = qf @ lin_w.T + lin_b ; out = log_softmax(logits)
//
// R4: 8 batch/block (512 blocks x 256 thr). Features computed from global x
// (stride-2 2x2 conv partitions x; L1 covers 4-channel stencil reuse), stored
// once to LDS as bf16 in MFMA A-fragment layout. lin_w -> bf16 B-fragments in
// LDS once per block. Linear layer = 7 MFMAs per wave (K split 4 ways), no
// cross-lane shuffles, no dynamic register indexing (R3's spill lesson).

#define NB   4096
#define BPB  8
#define GRID (NB / BPB)          // 512
#define KP   896                  // padded K (784 real), 4 waves x 224
#define RS   904                  // LDS row stride in bf16 elems (+8 anti-conflict)

using short8  = __attribute__((ext_vector_type(8))) short;
using float4v = __attribute__((ext_vector_type(4))) float;

__device__ __forceinline__ unsigned short f2bf(float f) {
    unsigned u = __builtin_bit_cast(unsigned, f);
    return (unsigned short)((u + 0x7FFFu + ((u >> 16) & 1u)) >> 16);
}

__global__ __launch_bounds__(256) void hqe_kernel(
    const float* __restrict__ x,       // [B, 784]
    const float* __restrict__ conv_w,  // [4,1,2,2]
    const float* __restrict__ conv_b,  // [4]
    const float* __restrict__ q_theta, // [4]
    const float* __restrict__ lin_w,   // [10, 784]
    const float* __restrict__ lin_b,   // [10]
    float* __restrict__ out)           // [B, 10]
{
    __shared__ __align__(16) unsigned short qf_s[16 * RS];  // A: [m=batch][k]
    __shared__ __align__(16) unsigned short w_s[16 * RS];   // B: [n=out][k]
    __shared__ __align__(16) float red_s[4 * 16 * 16];      // per-wave C tiles
    __shared__ float lg_s[BPB * 10];
    __shared__ float off_s[BPB];

    const int t = threadIdx.x;
    const int b0 = blockIdx.x * BPB;

    // ---- zero ONLY the k-pad columns [784,896) of the rows MFMA multiplies
    // against real data (qf rows 0..7, w rows 0..9); other garbage rows/cols
    // only affect discarded C entries. 112 bf16 = 56 dwords per row.
    for (int i = t; i < 8 * 56; i += 256) {
        const int r = i / 56, d = i - 56 * r;
        ((unsigned*)(qf_s + r * RS + 784))[d] = 0u;
    }
    for (int i = t; i < 10 * 56; i += 256) {
        const int r = i / 56, d = i - 56 * r;
        ((unsigned*)(w_s + r * RS + 784))[d] = 0u;
    }

    // ---- stage lin_w -> bf16 B-fragments: w_s[o][k], k<784
    {
        const float4* lw4 = (const float4*)lin_w;   // 1960 float4
        for (int i = t; i < 1960; i += 256) {
            const int o = i / 196;
            const int k0 = 4 * (i - 196 * o);
            const float4 v = lw4[i];
            const unsigned lo = f2bf(v.x) | ((unsigned)f2bf(v.y) << 16);
            const unsigned hi = f2bf(v.z) | ((unsigned)f2bf(v.w) << 16);
            *(uint2*)(w_s + o * RS + k0) = make_uint2(lo, hi);
        }
    }

    const float th0 = q_theta[0];
    const float ct1 = __cosf(q_theta[1]);
    const float th3 = q_theta[3];

    // ---- features: task (b,p) = quantum patch p of batch b0+b.
    // conv outputs read straight from global x (disjoint 2x2 stencils).
    for (int i = t; i < BPB * 196; i += 256) {
        const int b = i / 196;
        const int p = i - 196 * b;
        const int c = p / 49;
        const int s0 = 4 * p - 196 * c;       // spatial base in 14x14, mult of 4
        const float4 cw = ((const float4*)conv_w)[c];
        const float cb = conv_b[c];
        const float* xb = x + (size_t)(b0 + b) * 784;

        float a[4];
#pragma unroll
        for (int j = 0; j < 4; ++j) {
            const int s = s0 + j;
            const int h = s / 14;
            const int w2 = s - 14 * h;
            const float* xp = xb + h * 56 + 2 * w2;
            const float2 top = *(const float2*)xp;
            const float2 bot = *(const float2*)(xp + 28);
            a[j] = cb + top.x * cw.x + top.y * cw.y + bot.x * cw.z + bot.y * cw.w;
        }
        const float z0 = __cosf(a[0] + th0);
        const float z1 = ct1 * __cosf(a[1]);
        const float z2 = __cosf(a[2]);
        const float z3 = __cosf(a[3] + th3);
        const float f1 = z0 * z1;
        const float f2 = f1 * z2;
        const float f3 = z1 * z2 * z3;
        const unsigned lo = f2bf(z0) | ((unsigned)f2bf(f1) << 16);
        const unsigned hi = f2bf(f2) | ((unsigned)f2bf(f3) << 16);
        *(uint2*)(qf_s + b * RS + 4 * p) = make_uint2(lo, hi);
    }

    __syncthreads();

    // ---- MFMA: wave wv handles K slice [224*wv, 224*(wv+1)), 7 x 16x16x32.
    {
        const int wv = t >> 6;
        const int lane = t & 63;
        const int mrow = lane & 15;           // A row / B col for this lane
        const int qd = lane >> 4;
        const unsigned short* qrow = qf_s + mrow * RS;
        const unsigned short* wrow = w_s + mrow * RS;
        float4v acc = {0.f, 0.f, 0.f, 0.f};
        const int kbase = 224 * wv + 8 * qd;
#pragma unroll
        for (int kk = 0; kk < 7; ++kk) {
            const int k = kbase + 32 * kk;
            const short8 af = *(const short8*)(qrow + k);
            const short8 bf = *(const short8*)(wrow + k);
            acc = __builtin_amdgcn_mfma_f32_16x16x32_bf16(af, bf, acc, 0, 0, 0);
        }
        // C layout: col = lane&15 (=n), rows = qd*4 + reg (=m). Store [wv][n][m].
        *(float4v*)(red_s + (wv * 16 + mrow) * 16 + qd * 4) = acc;
    }

    __syncthreads();

    // ---- reduce 4 partial tiles; keep m<8 (batch), n<10 (outputs)
    {
        const int n = t >> 4;
        const int m = t & 15;
        if (m < BPB && n < 10) {
            const float s = red_s[0 * 256 + n * 16 + m] + red_s[1 * 256 + n * 16 + m]
                          + red_s[2 * 256 + n * 16 + m] + red_s[3 * 256 + n * 16 + m];
            lg_s[m * 10 + n] = s + lin_b[n];
        }
    }

    __syncthreads();

    if (t < BPB) {
        float mx = -INFINITY;
#pragma unroll
        for (int j = 0; j < 10; ++j) mx = fmaxf(mx, lg_s[t * 10 + j]);
        float sum = 0.0f;
#pragma unroll
        for (int j = 0; j < 10; ++j) sum += __expf(lg_s[t * 10 + j] - mx);
        off_s[t] = mx + __logf(sum);
    }

    __syncthreads();

    if (t < BPB * 10) {
        out[(size_t)b0 * 10 + t] = lg_s[t] - off_s[t / 10];
    }
}

extern "C" void kernel_launch(void* const* d_in, const int* in_sizes, int n_in,
                              void* d_out, int out_size, void* d_ws, size_t ws_size,
                              hipStream_t stream) {
    const float* x       = (const float*)d_in[0];
    const float* conv_w  = (const float*)d_in[1];
    const float* conv_b  = (const float*)d_in[2];
    const float* q_theta = (const float*)d_in[3];
    const float* lin_w   = (const float*)d_in[4];
    const float* lin_b   = (const float*)d_in[5];
    float* out = (float*)d_out;

    hqe_kernel<<<dim3(GRID), dim3(256), 0, stream>>>(x, conv_w, conv_b, q_theta,
                                                     lin_w, lin_b, out);
}

// Round 5
// 74.146 us; speedup vs baseline: 1.3154x; 1.0098x over previous
//
#include <hip/hip_runtime.h>
#include <math.h>

// HybridQuanvolutionEstimator — analytic circuit collapse + bf16 MFMA linear.
//
// z0=cos(a0+th0); z1=cos(th1)*cos(a1); z2=cos(a2); z3=cos(a3+th3)
// qf[b,4p..4p+3] = [z0, z0*z1, z0*z1*z2, z1*z2*z3]
// logits = qf @ lin_w.T + lin_b ; out = log_softmax(logits)
//
// R5 vs R4 (occupancy attack): BPB 8->4, grid 512->1024 (4 blocks/CU), LDS
// 62->~37 KB via one fused array: qf rows 0..3, lin_w rows 4..13, RS=808
// (rows 16B-aligned; start-bank stride 20 -> max 2-way aliasing = free).
// MFMA A/B over-reads of rows beyond the valid ones hit allocated garbage
// whose products land only in discarded C entries (m>=4 / n>=10).
// K = 25 interleaved 32-tiles over 4 waves; only pad cols [784,808) zeroed.

#define NB   4096
#define BPB  4
#define GRID (NB / BPB)          // 1024
#define RS   808                 // LDS row stride (bf16 elems); 1616 B, 16B-aligned

using short8  = __attribute__((ext_vector_type(8))) short;
using float4v = __attribute__((ext_vector_type(4))) float;

__device__ __forceinline__ unsigned short f2bf(float f) {
    unsigned u = __builtin_bit_cast(unsigned, f);
    return (unsigned short)((u + 0x7FFFu + ((u >> 16) & 1u)) >> 16);
}

__global__ __launch_bounds__(256) void hqe_kernel(
    const float* __restrict__ x,       // [B, 784]
    const float* __restrict__ conv_w,  // [4,1,2,2]
    const float* __restrict__ conv_b,  // [4]
    const float* __restrict__ q_theta, // [4]
    const float* __restrict__ lin_w,   // [10, 784]
    const float* __restrict__ lin_b,   // [10]
    float* __restrict__ out)           // [B, 10]
{
    // rows 0..3: qf (A, m=batch); rows 4..13: lin_w bf16 (B, n=output);
    // rows 14..19: never written, only read as discarded-C garbage.
    __shared__ __align__(16) unsigned short lds[20 * RS];   // 32320 B
    __shared__ __align__(16) float red_s[4 * 16 * 16];      // per-wave C tiles
    __shared__ float lg_s[BPB * 10];
    __shared__ float off_s[BPB];

    const int t = threadIdx.x;
    const int b0 = blockIdx.x * BPB;

    // ---- zero pad cols [784,808) of all 20 rows (wave-0 k=768 tile reads
    // elems 768..800; rest of pad harmless). 12 dwords x 20 rows.
    for (int i = t; i < 20 * 12; i += 256) {
        const int r = i / 12, d = i - 12 * r;
        ((unsigned*)(lds + r * RS + 784))[d] = 0u;
    }

    // ---- stage lin_w -> bf16 B rows (abs rows 4..13)
    {
        const float4* lw4 = (const float4*)lin_w;   // 1960 float4
        for (int i = t; i < 1960; i += 256) {
            const int o = i / 196;
            const int k0 = 4 * (i - 196 * o);
            const float4 v = lw4[i];
            const unsigned lo = f2bf(v.x) | ((unsigned)f2bf(v.y) << 16);
            const unsigned hi = f2bf(v.z) | ((unsigned)f2bf(v.w) << 16);
            *(uint2*)(lds + (4 + o) * RS + k0) = make_uint2(lo, hi);
        }
    }

    const float th0 = q_theta[0];
    const float ct1 = __cosf(q_theta[1]);
    const float th3 = q_theta[3];

    // ---- features: task (b,p); conv read straight from global x
    for (int i = t; i < BPB * 196; i += 256) {
        const int b = i / 196;
        const int p = i - 196 * b;
        const int c = p / 49;
        const int s0 = 4 * p - 196 * c;       // spatial base in 14x14
        const float4 cw = ((const float4*)conv_w)[c];
        const float cb = conv_b[c];
        const float* xb = x + (size_t)(b0 + b) * 784;

        float a[4];
#pragma unroll
        for (int j = 0; j < 4; ++j) {
            const int s = s0 + j;
            const int h = s / 14;
            const int w2 = s - 14 * h;
            const float* xp = xb + h * 56 + 2 * w2;
            const float2 top = *(const float2*)xp;
            const float2 bot = *(const float2*)(xp + 28);
            a[j] = cb + top.x * cw.x + top.y * cw.y + bot.x * cw.z + bot.y * cw.w;
        }
        const float z0 = __cosf(a[0] + th0);
        const float z1 = ct1 * __cosf(a[1]);
        const float z2 = __cosf(a[2]);
        const float z3 = __cosf(a[3] + th3);
        const float f1 = z0 * z1;
        const float f2 = f1 * z2;
        const float f3 = z1 * z2 * z3;
        const unsigned lo = f2bf(z0) | ((unsigned)f2bf(f1) << 16);
        const unsigned hi = f2bf(f2) | ((unsigned)f2bf(f3) << 16);
        *(uint2*)(lds + b * RS + 4 * p) = make_uint2(lo, hi);
    }

    __syncthreads();

    // ---- MFMA: K = 25 interleaved 32-tiles; wave wv takes k = 32*(wv+4*kk)
    {
        const int wv = t >> 6;
        const int lane = t & 63;
        const int mrow = lane & 15;
        const int qd = lane >> 4;
        const unsigned short* qrow = lds + mrow * RS + 8 * qd;        // A
        const unsigned short* wrow = lds + (4 + mrow) * RS + 8 * qd;  // B
        float4v acc = {0.f, 0.f, 0.f, 0.f};
#pragma unroll
        for (int kk = 0; kk < 7; ++kk) {
            const int k = 32 * (wv + 4 * kk);
            if (k < 800) {
                const short8 af = *(const short8*)(qrow + k);
                const short8 bf = *(const short8*)(wrow + k);
                acc = __builtin_amdgcn_mfma_f32_16x16x32_bf16(af, bf, acc, 0, 0, 0);
            }
        }
        // C layout: col = lane&15 (=n), rows = qd*4 + reg (=m). Store [wv][n][m].
        *(float4v*)(red_s + (wv * 16 + mrow) * 16 + qd * 4) = acc;
    }

    __syncthreads();

    // ---- reduce 4 partial tiles; keep m<4 (batch), n<10 (outputs)
    {
        const int n = t >> 4;
        const int m = t & 15;
        if (m < BPB && n < 10) {
            const float s = red_s[0 * 256 + n * 16 + m] + red_s[1 * 256 + n * 16 + m]
                          + red_s[2 * 256 + n * 16 + m] + red_s[3 * 256 + n * 16 + m];
            lg_s[m * 10 + n] = s + lin_b[n];
        }
    }

    __syncthreads();

    if (t < BPB) {
        float mx = -INFINITY;
#pragma unroll
        for (int j = 0; j < 10; ++j) mx = fmaxf(mx, lg_s[t * 10 + j]);
        float sum = 0.0f;
#pragma unroll
        for (int j = 0; j < 10; ++j) sum += __expf(lg_s[t * 10 + j] - mx);
        off_s[t] = mx + __logf(sum);
    }

    __syncthreads();

    if (t < BPB * 10) {
        out[(size_t)b0 * 10 + t] = lg_s[t] - off_s[t / 10];
    }
}

extern "C" void kernel_launch(void* const* d_in, const int* in_sizes, int n_in,
                              void* d_out, int out_size, void* d_ws, size_t ws_size,
                              hipStream_t stream) {
    const float* x       = (const float*)d_in[0];
    const float* conv_w  = (const float*)d_in[1];
    const float* conv_b  = (const float*)d_in[2];
    const float* q_theta = (const float*)d_in[3];
    const float* lin_w   = (const float*)d_in[4];
    const float* lin_b   = (const float*)d_in[5];
    float* out = (float*)d_out;

    hqe_kernel<<<dim3(GRID), dim3(256), 0, stream>>>(x, conv_w, conv_b, q_theta,
                                                     lin_w, lin_b, out);
}